// Round 3
// baseline (561.674 us; speedup 1.0000x reference)
//
#include <hip/hip_runtime.h>
#include <stdint.h>

#define NV 163842
#define EPSV 1e-5f

using short8 = __attribute__((ext_vector_type(8))) short;   // 8 bf16 (4 VGPRs)
using f32x4  = __attribute__((ext_vector_type(4))) float;   // MFMA acc

static __device__ __forceinline__ unsigned short f2bf(float f) {
    union { float f; unsigned int i; } v; v.f = f;
    return (unsigned short)((v.i + 0x7FFFu + ((v.i >> 16) & 1u)) >> 16);  // RNE
}
static __device__ __forceinline__ void bf2x(unsigned int w, float& a, float& b) {
    union { unsigned int i; float f; } lo, hi;
    lo.i = w << 16; hi.i = w & 0xFFFF0000u;
    a = lo.f; b = hi.f;
}
// pack two fp32 -> bf16x2 with round-half-up (+0x8000) and v_perm byte select
static __device__ __forceinline__ unsigned int pack2(float a, float b) {
    union { float f; unsigned int i; } ua, ub; ua.f = a; ub.f = b;
    return __builtin_amdgcn_perm(ub.i + 0x8000u, ua.i + 0x8000u, 0x07060302);
}

// ---- zero the stats accumulator ----
__global__ __launch_bounds__(256) void k_zero(float* __restrict__ ACC) {
    ACC[threadIdx.x] = 0.f;
    ACC[256 + threadIdx.x] = 0.f;
}

// ---- cast x fp32->bf16 into C cols [0,64); accumulate per-channel sum/sumsq ----
__global__ __launch_bounds__(256) void k_cast(const float* __restrict__ x,
                                              unsigned short* __restrict__ C,
                                              float* __restrict__ ACC) {
    const int t = threadIdx.x;
    const int wv = t >> 6, lane = t & 63;
    const int v = blockIdx.x * 64 + (t >> 2);
    const int c0 = (t & 3) * 16;
    float f[16];
    const bool valid = v < NV;
    if (valid) {
        const float4* p = (const float4*)(x + (size_t)v * 64 + c0);
#pragma unroll
        for (int i = 0; i < 4; ++i) {
            float4 q = p[i];
            f[i * 4 + 0] = q.x; f[i * 4 + 1] = q.y; f[i * 4 + 2] = q.z; f[i * 4 + 3] = q.w;
        }
        unsigned int o[8];
#pragma unroll
        for (int i = 0; i < 8; ++i)
            o[i] = ((unsigned int)f2bf(f[2 * i])) | (((unsigned int)f2bf(f[2 * i + 1])) << 16);
        uint4* dst = (uint4*)(C + (size_t)v * 256 + c0);
        dst[0] = uint4{o[0], o[1], o[2], o[3]};
        dst[1] = uint4{o[4], o[5], o[6], o[7]};
    } else {
#pragma unroll
        for (int i = 0; i < 16; ++i) f[i] = 0.f;
    }
    float s[16], s2[16];
#pragma unroll
    for (int i = 0; i < 16; ++i) { s[i] = f[i]; s2[i] = f[i] * f[i]; }
#pragma unroll
    for (int mask = 4; mask <= 32; mask <<= 1) {
#pragma unroll
        for (int i = 0; i < 16; ++i) {
            s[i]  += __shfl_xor(s[i],  mask);
            s2[i] += __shfl_xor(s2[i], mask);
        }
    }
    __shared__ float red[4 * 128];
    if ((lane >> 2) == 0) {
        int cb = (lane & 3) * 16;
#pragma unroll
        for (int i = 0; i < 16; ++i) {
            red[wv * 128 + cb + i]      = s[i];
            red[wv * 128 + 64 + cb + i] = s2[i];
        }
    }
    __syncthreads();
    if (t < 128) {
        float v4 = red[t] + red[128 + t] + red[256 + t] + red[384 + t];
        int c = t & 63, which = t >> 6;
        atomicAdd(&ACC[which * 256 + c], v4);
    }
}

// ---- transpose all four W [7cin,64] fp32 -> WT [64,7cin] bf16 ----
__global__ __launch_bounds__(256) void k_wt_all(const float* __restrict__ W1,
                                                const float* __restrict__ W2,
                                                const float* __restrict__ W3,
                                                const float* __restrict__ W4,
                                                unsigned short* __restrict__ WT) {
    int j = blockIdx.x * 256 + threadIdx.x;
    if (j >= 286720) return;
    const float* W; int jj, K7;
    if (j < 28672)       { W = W1; jj = j;          K7 = 448;  }
    else if (j < 86016)  { W = W2; jj = j - 28672;  K7 = 896;  }
    else if (j < 172032) { W = W3; jj = j - 86016;  K7 = 1344; }
    else                 { W = W4; jj = j - 172032; K7 = 1792; }
    int n = jj / K7, k = jj - n * K7;
    WT[j] = f2bf(W[(size_t)k * 64 + n]);
}

// ---- per-layer BN+LeakyReLU applied ONCE per element: C cols[0,CIN) -> Y[N,CIN] ----
template<int CIN>
__global__ __launch_bounds__(256) void k_apply(const unsigned short* __restrict__ C,
                                               const float* __restrict__ ACC,
                                               const float* __restrict__ g,
                                               const float* __restrict__ bglob,
                                               unsigned short* __restrict__ Y) {
    __shared__ float ssc[CIN], ssh[CIN];
    const int t = threadIdx.x;
    if (t < CIN) {
        float s = ACC[t], s2 = ACC[256 + t];
        float mu = s * (1.0f / NV);
        float var = fmaf(-mu, mu, s2 * (1.0f / NV));
        float sc = g[t] * rsqrtf(var + EPSV);
        ssc[t] = sc;
        ssh[t] = bglob[t] - mu * sc;
    }
    __syncthreads();
    constexpr int C8 = CIN / 8;
    int e = blockIdx.x * 256 + t;
    if (e >= NV * C8) return;
    int v = e / C8, c8 = e - v * C8;
    int ch = c8 * 8;
    uint4 u = *(const uint4*)(C + (size_t)v * 256 + ch);
    float f[8];
    bf2x(u.x, f[0], f[1]); bf2x(u.y, f[2], f[3]);
    bf2x(u.z, f[4], f[5]); bf2x(u.w, f[6], f[7]);
    unsigned int o[4];
#pragma unroll
    for (int jj = 0; jj < 4; ++jj) {
        float y0 = fmaf(f[2 * jj],     ssc[ch + 2 * jj],     ssh[ch + 2 * jj]);
        float y1 = fmaf(f[2 * jj + 1], ssc[ch + 2 * jj + 1], ssh[ch + 2 * jj + 1]);
        y0 = y0 > 0.f ? y0 : 0.2f * y0;
        y1 = y1 > 0.f ? y1 : 0.2f * y1;
        o[jj] = pack2(y0, y1);
    }
    *(uint4*)(Y + (size_t)v * CIN + ch) = uint4{o[0], o[1], o[2], o[3]};
}

// ---- gather-GEMM: A-frags direct global->VGPR (3-deep prefetch), B in LDS segments ----
template<int CIN, int GRP, bool FINAL>
__global__ __launch_bounds__(512, 4) void k_gg(const unsigned short* __restrict__ Y,
                                               const int* __restrict__ neigh,
                                               const unsigned short* __restrict__ WT,
                                               const float* __restrict__ wb,
                                               float* __restrict__ ACC,
                                               unsigned short* __restrict__ Cout,
                                               float* __restrict__ Fout) {
    constexpr int KB2 = CIN / 32;      // 32-k chunks per neighbor row
    constexpr int NC  = 7 * KB2;       // total chunks (14/28/42/56)
    constexpr int NSEG = NC / 14;      // 448-k segments
    constexpr int K7  = 7 * CIN;

    __shared__ int sIdx[1792];
    __shared__ unsigned short sW[64 * 456];   // 448 + 8 pad per row

    const int t = threadIdx.x;
    const int v0 = blockIdx.x * 256;

    for (int q = t; q < 1792; q += 512) {
        int gi = v0 * 7 + q;
        sIdx[q] = (gi < NV * 7) ? neigh[gi] : 0;
    }
    __syncthreads();

    const int wv = t >> 6, lane = t & 63;
    const int m = lane & 15, quad = lane >> 4;
    const int rb = wv * 32;
    const int qoff = quad * 8;

    // hoist this wave's gather indices into registers (14 per lane)
    int idx0[7], idx1[7];
#pragma unroll
    for (int r = 0; r < 7; ++r) {
        idx0[r] = sIdx[(rb + m) * 7 + r];
        idx1[r] = sIdx[(rb + 16 + m) * 7 + r];
    }

    f32x4 acc[2][4];
#pragma unroll
    for (int i = 0; i < 2; ++i)
#pragma unroll
        for (int j = 0; j < 4; ++j) acc[i][j] = f32x4{0.f, 0.f, 0.f, 0.f};

    auto loadA = [&](int c, short8& A0, short8& A1) {
        int r = c / KB2, kc = c - r * KB2;
        int ko = kc * 32 + qoff;
        A0 = *(const short8*)(Y + (size_t)idx0[r] * CIN + ko);
        A1 = *(const short8*)(Y + (size_t)idx1[r] * CIN + ko);
    };

    short8 a0[3], a1[3];
    loadA(0, a0[0], a1[0]);
    loadA(1, a0[1], a1[1]);
    loadA(2, a0[2], a1[2]);

#pragma unroll
    for (int seg = 0; seg < NSEG; ++seg) {
        __syncthreads();                       // sW safe to overwrite
        {   // stage 448-k B segment: 7 x (global b128 -> ds_write b128) per wave
            const int n = wv * 8 + (lane >> 3);
            const int ch0 = lane & 7;
            const unsigned short* src = WT + (size_t)n * K7 + seg * 448;
            unsigned short* dst = sW + n * 456;
#pragma unroll
            for (int p = 0; p < 7; ++p) {
                int ch16 = p * 8 + ch0;
                *(uint4*)(dst + ch16 * 8) = *(const uint4*)(src + ch16 * 8);
            }
        }
        __syncthreads();
#pragma unroll
        for (int cc = 0; cc < 14; ++cc) {
            const int c = seg * 14 + cc;
            short8 na0, na1;
            if (c + 3 < NC) loadA(c + 3, na0, na1);   // in flight across MFMA + barriers
            const int buf = c % 3;
#pragma unroll
            for (int ct = 0; ct < 4; ++ct) {
                short8 bf = *(const short8*)(sW + (ct * 16 + m) * 456 + cc * 32 + qoff);
                acc[0][ct] = __builtin_amdgcn_mfma_f32_16x16x32_bf16(a0[buf], bf, acc[0][ct], 0, 0, 0);
                acc[1][ct] = __builtin_amdgcn_mfma_f32_16x16x32_bf16(a1[buf], bf, acc[1][ct], 0, 0, 0);
            }
            if (c + 3 < NC) { a0[buf] = na0; a1[buf] = na1; }
        }
    }

    // epilogue: bias, write, per-channel stats for the produced 64-col group
    __syncthreads();   // sW dead; reuse as reduction scratch
    float bsum[4]  = {0.f, 0.f, 0.f, 0.f};
    float b2sum[4] = {0.f, 0.f, 0.f, 0.f};
#pragma unroll
    for (int mt = 0; mt < 2; ++mt) {
#pragma unroll
        for (int ct = 0; ct < 4; ++ct) {
            int col = ct * 16 + m;
            float bv = wb[col];
#pragma unroll
            for (int j = 0; j < 4; ++j) {
                int vr = v0 + wv * 32 + mt * 16 + quad * 4 + j;
                float val = acc[mt][ct][j] + bv;
                if (vr < NV) {
                    if (FINAL) {
                        Fout[(size_t)vr * 64 + col] = val;
                    } else {
                        Cout[(size_t)vr * 256 + GRP * 64 + col] = f2bf(val);
                        bsum[ct] += val; b2sum[ct] += val * val;
                    }
                }
            }
        }
    }
    if (!FINAL) {
#pragma unroll
        for (int ct = 0; ct < 4; ++ct) {   // reduce over quads
            bsum[ct]  += __shfl_xor(bsum[ct], 16);
            bsum[ct]  += __shfl_xor(bsum[ct], 32);
            b2sum[ct] += __shfl_xor(b2sum[ct], 16);
            b2sum[ct] += __shfl_xor(b2sum[ct], 32);
        }
        float* red = (float*)sW;
        if (quad == 0) {
#pragma unroll
            for (int ct = 0; ct < 4; ++ct) {
                red[wv * 128 + ct * 16 + m]        = bsum[ct];
                red[1024 + wv * 128 + ct * 16 + m] = b2sum[ct];
            }
        }
        __syncthreads();
        if (t < 128) {
            int c = t & 63, which = t >> 6;
            float s = 0.f;
#pragma unroll
            for (int w = 0; w < 8; ++w) s += red[which * 1024 + w * 128 + c];
            atomicAdd(&ACC[which * 256 + GRP * 64 + c], s);
        }
    }
}

extern "C" void kernel_launch(void* const* d_in, const int* in_sizes, int n_in,
                              void* d_out, int out_size, void* d_ws, size_t ws_size,
                              hipStream_t stream) {
    const float* x     = (const float*)d_in[0];
    const int*   neigh = (const int*)d_in[1];
    const float* G[4]  = {(const float*)d_in[2],  (const float*)d_in[6],
                          (const float*)d_in[10], (const float*)d_in[14]};
    const float* B[4]  = {(const float*)d_in[3],  (const float*)d_in[7],
                          (const float*)d_in[11], (const float*)d_in[15]};
    const float* W[4]  = {(const float*)d_in[4],  (const float*)d_in[8],
                          (const float*)d_in[12], (const float*)d_in[16]};
    const float* WB[4] = {(const float*)d_in[5],  (const float*)d_in[9],
                          (const float*)d_in[13], (const float*)d_in[17]};
    float* out = (float*)d_out;

    char* ws = (char*)d_ws;
    size_t off = 0;
    unsigned short* C  = (unsigned short*)(ws + off); off += (size_t)NV * 256 * 2;  // raw concat x|x1|x2|x3 (bf16)
    unsigned short* Yb = (unsigned short*)(ws + off); off += (size_t)NV * 256 * 2;  // post-BN compact rows
    unsigned short* WT = (unsigned short*)(ws + off); off += (size_t)286720 * 2;    // transposed bf16 W (all 4)
    float* ACC         = (float*)(ws + off);          off += 512 * 4;               // sum[256], sumsq[256]

    k_zero<<<1, 256, 0, stream>>>(ACC);
    k_cast<<<(NV + 63) / 64, 256, 0, stream>>>(x, C, ACC);
    k_wt_all<<<(286720 + 255) / 256, 256, 0, stream>>>(W[0], W[1], W[2], W[3], WT);

    const int GG = (NV + 255) / 256;
#define APPLY(CIN, LI) k_apply<CIN><<<((NV * (CIN / 8)) + 255) / 256, 256, 0, stream>>>(C, ACC, G[LI], B[LI], Yb)
    APPLY(64, 0);
    k_gg< 64, 1, false><<<GG, 512, 0, stream>>>(Yb, neigh, WT,          WB[0], ACC, C, nullptr);
    APPLY(128, 1);
    k_gg<128, 2, false><<<GG, 512, 0, stream>>>(Yb, neigh, WT + 28672,  WB[1], ACC, C, nullptr);
    APPLY(192, 2);
    k_gg<192, 3, false><<<GG, 512, 0, stream>>>(Yb, neigh, WT + 86016,  WB[2], ACC, C, nullptr);
    APPLY(256, 3);
    k_gg<256, 0, true ><<<GG, 512, 0, stream>>>(Yb, neigh, WT + 172032, WB[3], ACC, nullptr, out);
#undef APPLY
}